// Round 4
// baseline (708.602 us; speedup 1.0000x reference)
//
#include <hip/hip_runtime.h>

#define D 128

// ---------------------------------------------------------------------------
// Kernel 0: column means of dist_embedding [M,6] and dist_embedding_norm [M,1]
// ---------------------------------------------------------------------------
__global__ void means_kernel(const float* __restrict__ de, const float* __restrict__ den,
                             int M, float* __restrict__ out7) {
    __shared__ float sm[256][8];
    float a[7];
#pragma unroll
    for (int j = 0; j < 7; ++j) a[j] = 0.f;
    for (int r = threadIdx.x; r < M; r += 256) {
#pragma unroll
        for (int j = 0; j < 6; ++j) a[j] += de[r * 6 + j];
        a[6] += den[r];
    }
#pragma unroll
    for (int j = 0; j < 7; ++j) sm[threadIdx.x][j] = a[j];
    __syncthreads();
    for (int s = 128; s > 0; s >>= 1) {
        if (threadIdx.x < (unsigned)s) {
#pragma unroll
            for (int j = 0; j < 7; ++j) sm[threadIdx.x][j] += sm[threadIdx.x + s][j];
        }
        __syncthreads();
    }
    if (threadIdx.x < 7) out7[threadIdx.x] = sm[0][threadIdx.x] / (float)M;
}

// ---------------------------------------------------------------------------
// Kernel 1: segment bounds. off[b] = first node index with seg >= b, off[B] = N.
// ---------------------------------------------------------------------------
__global__ void bounds_kernel(const int* __restrict__ seg, int N, int B,
                              int* __restrict__ off) {
    int i = blockIdx.x * blockDim.x + threadIdx.x;
    if (i > N) return;
    int cur  = (i < N) ? seg[i]     : B;
    int prev = (i > 0) ? seg[i - 1] : -1;
    for (int j = prev + 1; j <= cur; ++j) off[j] = i;
}

// ---------------------------------------------------------------------------
// Kernel 2: PURE streaming pool partials. 2 blocks per segment (halves
// interleaved at 16-row granularity). Since we use the shift-free softmax
// (validated r2/r3: absmax 1.9e-6), partials (s, sum e*x) are additive, so
// halves combine exactly in kernel 3. Quarter-wave owns a row; lane holds
// 8 cols via two float4 loads; loads unconditional (clamped), mask only
// zeroes e. Writes 129 floats per block to d_ws (zeros if empty half).
// ---------------------------------------------------------------------------
__global__ void stream_kernel(const float* __restrict__ x, const int* __restrict__ mask,
                              const int* __restrict__ off,
                              const float* __restrict__ gate_w, const float* __restrict__ gate_b,
                              float* __restrict__ partials) {
    const int b    = blockIdx.x >> 1;
    const int h    = blockIdx.x & 1;
    const int tid  = threadIdx.x;
    const int wv   = tid >> 6;
    const int lane = tid & 63;
    const int q    = lane >> 4;
    const int l16  = lane & 15;
    const int part = (wv << 2) | q;

    const int start = off[b];
    const int end   = off[b + 1];

    const float4 gwA = ((const float4*)gate_w)[l16];
    const float4 gwB = ((const float4*)gate_w)[16 + l16];
    const float  gb  = gate_b[0];

    float  s    = 0.f;
    float4 accA = {0.f, 0.f, 0.f, 0.f};
    float4 accB = {0.f, 0.f, 0.f, 0.f};
    const int last = end - 1;

#pragma unroll 4
    for (int i = start + (h << 4); i < end; i += 32) {
        const int row = i + (wv << 2) + q;
        const int r   = min(row, last);           // tail lanes re-read last row (L1 hit)
        const float* xr = x + (size_t)r * D;
        const float4 xa = ((const float4*)xr)[l16];
        const float4 xb = ((const float4*)xr)[16 + l16];
        const int    mk = mask[r];
        float p = xa.x * gwA.x + xa.y * gwA.y + xa.z * gwA.z + xa.w * gwA.w
                + xb.x * gwB.x + xb.y * gwB.y + xb.z * gwB.z + xb.w * gwB.w;
#pragma unroll
        for (int o = 8; o > 0; o >>= 1) p += __shfl_xor(p, o);   // 16-lane reduce
        const float e = (row < end && mk != 0) ? __expf(p + gb) : 0.f;
        s      += e;
        accA.x += e * xa.x; accA.y += e * xa.y; accA.z += e * xa.z; accA.w += e * xa.w;
        accB.x += e * xb.x; accB.y += e * xb.y; accB.z += e * xb.z; accB.w += e * xb.w;
    }

    __shared__ float sacc[16][D + 4];
    __shared__ float ss[16];
    *(float4*)&sacc[part][l16 * 4]      = accA;
    *(float4*)&sacc[part][64 + l16 * 4] = accB;
    if (l16 == 0) ss[part] = s;
    __syncthreads();

    float* outp = partials + (size_t)blockIdx.x * 132;
    if (tid < D) {
        float A = 0.f;
#pragma unroll
        for (int k = 0; k < 16; ++k) A += sacc[k][tid];
        outp[tid] = A;
    } else if (tid == D) {
        float S = 0.f;
#pragma unroll
        for (int k = 0; k < 16; ++k) S += ss[k];
        outp[D] = S;
    }
}

// ---------------------------------------------------------------------------
// Kernel 3: combine two partials per segment, normalize, fused MLPs, outputs.
// ---------------------------------------------------------------------------
__global__ void combine_mlp_kernel(const float* __restrict__ partials,
                                   const float* __restrict__ w1, const float* __restrict__ b1,
                                   const float* __restrict__ w2, const float* __restrict__ b2,
                                   const float* __restrict__ w1n, const float* __restrict__ b1n,
                                   const float* __restrict__ w2n, const float* __restrict__ b2n,
                                   const float* __restrict__ means,
                                   float* __restrict__ out_vec, float* __restrict__ out_norm) {
    const int b   = blockIdx.x;
    const int tid = threadIdx.x;
    const float* p0 = partials + (size_t)(2 * b) * 132;
    const float* p1 = p0 + 132;

    __shared__ float xs[D];
    if (tid < D) {
        const float S = fmaxf(p0[D] + p1[D], 1e-12f);   // empty/all-masked -> 0
        xs[tid] = (p0[tid] + p1[tid]) / S;
    }
    __syncthreads();

    __shared__ float hid[D], hidn[D];
    if (tid < D) {
        float a1 = b1[tid];
#pragma unroll 8
        for (int i = 0; i < D; ++i) a1 += xs[i] * w1[i * D + tid];
        hid[tid] = fmaxf(a1, 0.f);
    } else {
        const int hh = tid - D;
        float a1n = b1n[hh];
#pragma unroll 8
        for (int i = 0; i < D; ++i) a1n += xs[i] * w1n[i * D + hh];
        hidn[hh] = fmaxf(a1n, 0.f);
    }
    __syncthreads();

    if (tid < 112) {
        const int g = tid >> 4, l = tid & 15;
        float o = 0.f;
        if (g < 6) {
#pragma unroll
            for (int k = 0; k < 8; ++k) { const int i = l * 8 + k; o += hid[i] * w2[i * 6 + g]; }
        } else {
#pragma unroll
            for (int k = 0; k < 8; ++k) { const int i = l * 8 + k; o += hidn[i] * w2n[i]; }
        }
#pragma unroll
        for (int of = 8; of > 0; of >>= 1) o += __shfl_xor(o, of);
        if (l == 0) {
            if (g < 6) out_vec[b * 6 + g] = (o + b2[g]) * means[g];
            else       out_norm[b]        = (o + b2n[0]) * means[6];
        }
    }
}

extern "C" void kernel_launch(void* const* d_in, const int* in_sizes, int n_in,
                              void* d_out, int out_size, void* d_ws, size_t ws_size,
                              hipStream_t stream) {
    const float* x      = (const float*)d_in[0];
    const int*   mask   = (const int*)  d_in[1];
    const int*   seg    = (const int*)  d_in[2];
    const float* de     = (const float*)d_in[3];
    const float* den    = (const float*)d_in[4];
    const float* gate_w = (const float*)d_in[5];
    const float* gate_b = (const float*)d_in[6];
    const float* w1     = (const float*)d_in[7];
    const float* b1     = (const float*)d_in[8];
    const float* w2     = (const float*)d_in[9];
    const float* b2     = (const float*)d_in[10];
    const float* w1n    = (const float*)d_in[11];
    const float* b1n    = (const float*)d_in[12];
    const float* w2n    = (const float*)d_in[13];
    const float* b2n    = (const float*)d_in[14];

    const int N  = in_sizes[1];        // 1,000,000 nodes
    const int M  = in_sizes[4];        // 1024 dist-embedding rows
    const int Bn = out_size / 7;       // 4096 segments

    float* means    = (float*)d_ws;                    // 7 floats @ 0
    int*   off      = (int*)d_ws + 16;                 // B+1 ints
    float* partials = (float*)d_ws + 8192;             // 2*B * 132 floats (4.3 MB)
    float* out_vec  = (float*)d_out;                   // [B,6]
    float* out_norm = (float*)d_out + (size_t)Bn * 6;  // [B,1]

    means_kernel<<<1, 256, 0, stream>>>(de, den, M, means);
    bounds_kernel<<<(N + 256) / 256, 256, 0, stream>>>(seg, N, Bn, off);
    stream_kernel<<<2 * Bn, 256, 0, stream>>>(x, mask, off, gate_w, gate_b, partials);
    combine_mlp_kernel<<<Bn, 256, 0, stream>>>(partials, w1, b1, w2, b2,
                                               w1n, b1n, w2n, b2n, means,
                                               out_vec, out_norm);
}